// Round 8
// baseline (199.729 us; speedup 1.0000x reference)
//
#include <hip/hip_runtime.h>

typedef __bf16 bf16x8 __attribute__((ext_vector_type(8)));
typedef float f32x4 __attribute__((ext_vector_type(4)));

#define F_FIELDS 26
#define V_FIELD  8000
#define V_TOT    208000
#define D_EMBD   16
#define DNN_IN   10816   // 26*26*16
#define BS       4096
#define ND       13
#define H1_DIM   256
#define H2_DIM   128
#define NP1      8       // gemm1 split-K planes

__device__ __forceinline__ unsigned short f2bf(float f) {
  unsigned u = __float_as_uint(f);
  u += 0x7fffu + ((u >> 16) & 1u);      // round-to-nearest-even
  return (unsigned short)(u >> 16);
}
__device__ __forceinline__ float bf2f(unsigned short h) {
  return __uint_as_float(((unsigned)h) << 16);
}
__device__ __forceinline__ float bflo(unsigned u) { return __uint_as_float(u << 16); }
__device__ __forceinline__ float bfhi(unsigned u) { return __uint_as_float(u & 0xffff0000u); }
__device__ __forceinline__ unsigned packbf(float a, float b) {
  return (unsigned)f2bf(a) | ((unsigned)f2bf(b) << 16);
}

__device__ __forceinline__ void gload16(const void* g, void* l) {
  __builtin_amdgcn_global_load_lds(
      (const __attribute__((address_space(1))) unsigned int*)g,
      (__attribute__((address_space(3))) unsigned int*)l, 16, 0, 0);
}

__device__ __forceinline__ float dot8bf(uint4 a, uint4 b) {
  const unsigned* pa = (const unsigned*)&a;
  const unsigned* pb = (const unsigned*)&b;
  float s = 0.f;
#pragma unroll
  for (int k = 0; k < 4; ++k)
    s += bflo(pa[k]) * bflo(pb[k]) + bfhi(pa[k]) * bfhi(pb[k]);
  return s;
}

// ------- gather: A tensor + fm1 + fm2 + W1/W2/dense-W bf16 conversion -------
// All workspace writes are NON-TEMPORAL: keep L3 capacity for the emb rows
// (~139 MB distinct working set, L3-resident across graph replays).
__global__ __launch_bounds__(256) void k_gather(
    const int* __restrict__ Xs, const float* __restrict__ emb,
    const float* __restrict__ fm1_emb, const float* __restrict__ bias,
    const float* __restrict__ fm1dW, const float* __restrict__ fm1db,
    const float* __restrict__ Xd,
    const float* __restrict__ W1, const float* __restrict__ W2,
    const float* __restrict__ dW, const float* __restrict__ db_,
    unsigned short* __restrict__ W1b, unsigned short* __restrict__ W2b,
    unsigned short* __restrict__ dWb,
    unsigned short* __restrict__ Abf, float* __restrict__ fm12) {
  const int b = blockIdx.x;
  const int tid = threadIdx.x;
  const int lane = tid & 63, wave = tid >> 6;
  __shared__ int   sidx[F_FIELDS];
  __shared__ float sc1[F_FIELDS];
  __shared__ __align__(16) unsigned short As[676 * 16];  // bf16, 21.6 KB
  __shared__ float wred[4];

  if (tid < F_FIELDS) {
    int v = Xs[b * F_FIELDS + tid] + tid * V_FIELD;
    sidx[tid] = v;
    sc1[tid] = fm1_emb[v];
  }
  __syncthreads();

  const int q = tid & 3, rbase = tid >> 2;   // 4 lanes per row (float4 each)
  float4 vv[11];
#pragma unroll
  for (int it = 0; it < 11; ++it) {          // issue all gathers first (MLP)
    int r = rbase + it * 64;
    if (r < 676) {
      int i = r / 26, j = r - i * 26;
      const float* src = emb + ((size_t)i * V_TOT + sidx[j]) * D_EMBD + q * 4;
      vv[it] = *(const float4*)src;
    }
  }
  // W1/W2 -> bf16 conversion (NT stores; re-read within same replay only)
  const int n1 = H1_DIM * DNN_IN, n2 = H2_DIM * H1_DIM;
  for (int t = b * 256 + tid; t < n1 + n2; t += BS * 256) {
    if (t < n1) __builtin_nontemporal_store(f2bf(W1[t]), &W1b[t]);
    else        __builtin_nontemporal_store(f2bf(W2[t - n1]), &W2b[t - n1]);
  }
  // dense-W augmented bf16 table (K=32): [0..12]=w, [13]=db, [14..31]=0
  for (int e = b * 256 + tid; e < DNN_IN; e += BS * 256) {
    unsigned short row[32];
#pragma unroll
    for (int k = 0; k < 13; ++k) row[k] = f2bf(dW[e * 13 + k]);
    row[13] = f2bf(db_[e]);
#pragma unroll
    for (int k = 14; k < 32; ++k) row[k] = 0;
#pragma unroll
    for (int k = 0; k < 32; ++k) __builtin_nontemporal_store(row[k], &dWb[e * 32 + k]);
  }
#pragma unroll
  for (int it = 0; it < 11; ++it) {
    int r = rbase + it * 64;
    if (r < 676) {
      unsigned lo = packbf(vv[it].x, vv[it].y);
      unsigned hi = packbf(vv[it].z, vv[it].w);
      unsigned long long pk = (unsigned long long)lo |
                              ((unsigned long long)hi << 32);
      *(unsigned long long*)&As[r * 16 + q * 4] = pk;
      __builtin_nontemporal_store(
          pk, (unsigned long long*)&Abf[(size_t)b * DNN_IN + r * 16 + q * 4]);
    }
  }
  __syncthreads();

  // fm2 = sum_{i<j} dot(A[b,i,j,:], A[b,j,i,:]) ; 325 pairs (bf16 products)
  float acc2 = 0.f;
  for (int p = tid; p < 325; p += 256) {
    float disc = sqrtf((float)(2601 - 8 * p));   // exact for perfect squares
    int i = (int)((51.f - disc) * 0.5f);
    int cum = 25 * i - ((i * (i - 1)) >> 1);
    int j = i + 1 + (p - cum);
    const unsigned short* r1 = &As[(i * 26 + j) * 16];
    const unsigned short* r2 = &As[(j * 26 + i) * 16];
    acc2 += dot8bf(*(const uint4*)r1, *(const uint4*)r2);
    acc2 += dot8bf(*(const uint4*)(r1 + 8), *(const uint4*)(r2 + 8));
  }
#pragma unroll
  for (int off = 32; off; off >>= 1) acc2 += __shfl_down(acc2, off);
  if (lane == 0) wred[wave] = acc2;
  __syncthreads();
  if (tid == 0) {
    float fm2 = wred[0] + wred[1] + wred[2] + wred[3];
    float f1 = bias[0] + fm1db[0];
#pragma unroll
    for (int j = 0; j < F_FIELDS; ++j) f1 += sc1[j];
    for (int k = 0; k < ND; ++k) f1 += Xd[b * ND + k] * fm1dW[k];
    fm12[b] = f1 + fm2;
  }
}

// ---- GEMM1 fused-dense: Y1part = (A + relu(Xd@dW^T+db)) @ W1^T -------------
// 64x256 tile, depth-2 3-buffer pipeline, split-K 8 (plane = id&7 per XCD).
__global__ __launch_bounds__(256) void k_gemm1(
    const unsigned short* __restrict__ A, const unsigned short* __restrict__ B,
    const unsigned short* __restrict__ dWb, const float* __restrict__ Xd,
    unsigned short* __restrict__ C) {
  __shared__ __align__(16) unsigned short sA[3][64 * 32];    // 12 KB
  __shared__ __align__(16) unsigned short sB[3][256 * 32];   // 48 KB
  __shared__ __align__(16) unsigned short sWd[3][1024];      // 6 KB (32e x 32k)
  __shared__ __align__(16) unsigned short sD[64 * 32];       // 4 KB (E-tile)
  __shared__ __align__(16) unsigned short sXd[64 * 32];      // 4 KB (augmented)
  const int tid = threadIdx.x;
  const int lane = tid & 63, w = tid >> 6;
  const int id = blockIdx.x;
  const int p = id & 7, mt = id >> 3;
  const int m0 = mt * 64;
  const int s0 = (338 * p) >> 3, s1 = (338 * (p + 1)) >> 3;
  C += (size_t)p * ((size_t)BS * H1_DIM);

  // stage augmented Xd rows (once): [s][0..12]=xd, [13]=1.0, [14..31]=0
  if (tid < 64) {
    const float* xr = Xd + (size_t)(m0 + tid) * ND;
    unsigned short row[32];
#pragma unroll
    for (int k = 0; k < 13; ++k) row[k] = f2bf(xr[k]);
    row[13] = 0x3F80;                          // bf16(1.0)
#pragma unroll
    for (int k = 14; k < 32; ++k) row[k] = 0;
#pragma unroll
    for (int k = 0; k < 32; ++k) sXd[tid * 32 + k] = row[k];
  }
  __syncthreads();

  const int q = tid & 3, rr = tid >> 2;       // rr 0..63
  const unsigned short* gA  = A + (size_t)(m0 + rr) * DNN_IN + q * 8;
  const unsigned short* gB0 = B + (size_t)rr * DNN_IN + q * 8;
  const int fr = lane & 15, fk = lane >> 4;
  const int oA = fr * 32 + fk * 8;             // frag base (rows=samples)
  const int oB = (w * 64 + fr) * 32 + fk * 8;

  // D-gen (swapped operands): A-op = dW_aug rows, B-op = Xd_aug samples.
  const bf16x8 bvd = *(const bf16x8*)&sXd[(w * 16 + fr) * 32 + fk * 8];
  const int erow = (w * 16 + fr) * 32;         // sD row base for this lane
  const int ecol = fk * 4;                     // 4 consecutive e per mfma reg

  f32x4 acc[4][4] = {};
  const f32x4 zf = {0.f, 0.f, 0.f, 0.f};

#define STAGE1(ks, bi) do { const int ko_ = (ks) * 32;                      \
    gload16(gA + ko_, &sA[bi][tid * 8]);                                    \
    gload16(gB0 + ko_, &sB[bi][tid * 8]);                                   \
    gload16(gB0 + (size_t)64 * DNN_IN + ko_, &sB[bi][2048 + tid * 8]);      \
    gload16(gB0 + (size_t)128 * DNN_IN + ko_, &sB[bi][4096 + tid * 8]);     \
    gload16(gB0 + (size_t)192 * DNN_IN + ko_, &sB[bi][6144 + tid * 8]);     \
    gload16(dWb + (size_t)ko_ * 32 + (size_t)lane * 8, &sWd[bi][lane * 8]); \
    gload16(dWb + (size_t)ko_ * 32 + 512 + (size_t)lane * 8,                \
            &sWd[bi][512 + lane * 8]); } while (0)

  STAGE1(s0, 0);
  if (s0 + 1 < s1) STAGE1(s0 + 1, 1);
  if (s0 + 2 < s1) STAGE1(s0 + 2, 2);

  int bi = 0;
  for (int ks = s0; ks < s1; ++ks) {
    if (ks + 2 < s1)      asm volatile("s_waitcnt vmcnt(14)" ::: "memory");
    else if (ks + 1 < s1) asm volatile("s_waitcnt vmcnt(7)" ::: "memory");
    else                  asm volatile("s_waitcnt vmcnt(0)" ::: "memory");
    __builtin_amdgcn_sched_barrier(0);
    __builtin_amdgcn_s_barrier();             // bar1: buf bi staged
    bf16x8 aw0 = *(const bf16x8*)&sWd[bi][fr * 32 + fk * 8];
    bf16x8 aw1 = *(const bf16x8*)&sWd[bi][(16 + fr) * 32 + fk * 8];
    bf16x8 bv[4];
#pragma unroll
    for (int ni = 0; ni < 4; ++ni) bv[ni] = *(const bf16x8*)&sB[bi][oB + ni * 512];
    uint2 a0 = *(const uint2*)&sA[bi][erow + ecol];
    uint2 a1 = *(const uint2*)&sA[bi][erow + 16 + ecol];
    asm volatile("s_waitcnt lgkmcnt(0)" ::: "memory");
    __builtin_amdgcn_sched_barrier(0);
    f32x4 d0 = __builtin_amdgcn_mfma_f32_16x16x32_bf16(aw0, bvd, zf, 0, 0, 0);
    f32x4 d1 = __builtin_amdgcn_mfma_f32_16x16x32_bf16(aw1, bvd, zf, 0, 0, 0);
    uint2 e0, e1;
    e0.x = packbf(bflo(a0.x) + fmaxf(d0[0], 0.f), bfhi(a0.x) + fmaxf(d0[1], 0.f));
    e0.y = packbf(bflo(a0.y) + fmaxf(d0[2], 0.f), bfhi(a0.y) + fmaxf(d0[3], 0.f));
    e1.x = packbf(bflo(a1.x) + fmaxf(d1[0], 0.f), bfhi(a1.x) + fmaxf(d1[1], 0.f));
    e1.y = packbf(bflo(a1.y) + fmaxf(d1[2], 0.f), bfhi(a1.y) + fmaxf(d1[3], 0.f));
    *(uint2*)&sD[erow + ecol] = e0;
    *(uint2*)&sD[erow + 16 + ecol] = e1;
    asm volatile("s_waitcnt lgkmcnt(0)" ::: "memory");
    __builtin_amdgcn_sched_barrier(0);
    __builtin_amdgcn_s_barrier();             // bar2: sD(E) complete
    if (ks + 3 < s1) STAGE1(ks + 3, bi);
    bf16x8 ev[4];
#pragma unroll
    for (int mi = 0; mi < 4; ++mi) ev[mi] = *(const bf16x8*)&sD[oA + mi * 512];
    asm volatile("s_waitcnt lgkmcnt(0)" ::: "memory");
    __builtin_amdgcn_sched_barrier(0);
#pragma unroll
    for (int mi = 0; mi < 4; ++mi)
#pragma unroll
      for (int ni = 0; ni < 4; ++ni)
        acc[mi][ni] = __builtin_amdgcn_mfma_f32_16x16x32_bf16(
            ev[mi], bv[ni], acc[mi][ni], 0, 0, 0);
    bi = bi + 1; if (bi == 3) bi = 0;
  }
#pragma unroll
  for (int mi = 0; mi < 4; ++mi)
#pragma unroll
    for (int ni = 0; ni < 4; ++ni)
#pragma unroll
      for (int r = 0; r < 4; ++r) {
        int row = m0 + mi * 16 + fk * 4 + r;
        int col = w * 64 + ni * 16 + fr;
        __builtin_nontemporal_store(f2bf(acc[mi][ni][r]),
                                    &C[(size_t)row * H1_DIM + col]);
      }
#undef STAGE1
}

// -------- stat1: reduce 8 bf16 planes + b1 -> Y1, per-group partials --------
__global__ __launch_bounds__(256) void k_stat1(
    const unsigned short* __restrict__ Yp, const float* __restrict__ b1,
    float* __restrict__ Y1, float* __restrict__ ps, float* __restrict__ pq) {
  const int g = blockIdx.x, n = threadIdx.x;   // 256 groups x 16 rows
  const size_t plane = (size_t)BS * H1_DIM;
  float s = 0.f, s2 = 0.f;
  float bn = b1[n];
  for (int bb = 0; bb < 16; ++bb) {
    size_t o = (size_t)(g * 16 + bb) * H1_DIM + n;
    float y = bn;
#pragma unroll
    for (int pp = 0; pp < NP1; ++pp)
      y += bf2f(__builtin_nontemporal_load(&Yp[o + pp * plane]));
    __builtin_nontemporal_store(y, &Y1[o]);
    s += y; s2 += y * y;
  }
  ps[g * H1_DIM + n] = s;
  pq[g * H1_DIM + n] = s2;
}

// ---- apply1: deterministic inline stats reduce + BN1 + relu -> H1 (bf16) ---
__global__ __launch_bounds__(256) void k_apply1(
    const float* __restrict__ Y1, const float* __restrict__ ps,
    const float* __restrict__ pq, const float* __restrict__ g1,
    const float* __restrict__ be1, unsigned short* __restrict__ H1b) {
  const int g = blockIdx.x, n = threadIdx.x;
  float s = 0.f, s2 = 0.f;
  for (int gg = 0; gg < 256; ++gg) {           // fixed order -> deterministic
    s += ps[gg * H1_DIM + n];
    s2 += pq[gg * H1_DIM + n];
  }
  float m = s * (1.f / BS);
  float v = s2 * (1.f / BS) - m * m;
  float r = rsqrtf(v + 1e-5f);
  float ga = g1[n], bb_ = be1[n];
  for (int bb = 0; bb < 16; ++bb) {
    size_t o = (size_t)(g * 16 + bb) * H1_DIM + n;
    float h = (__builtin_nontemporal_load(&Y1[o]) - m) * r * ga + bb_;
    __builtin_nontemporal_store(f2bf(fmaxf(h, 0.f)), &H1b[o]);
  }
}

// -------- GEMM2 (32 blocks) + bias + per-block partial column stats ---------
__global__ __launch_bounds__(256) void k_gemm2(
    const unsigned short* __restrict__ A, const unsigned short* __restrict__ B,
    const float* __restrict__ b2, float* __restrict__ Y2,
    float* __restrict__ ps, float* __restrict__ pq) {
  __shared__ __align__(16) unsigned short sA[2][128 * 32];
  __shared__ __align__(16) unsigned short sB[2][128 * 32];
  __shared__ float redS[8][H2_DIM];
  __shared__ float redQ[8][H2_DIM];
  const int tid = threadIdx.x;
  const int lane = tid & 63, wave = tid >> 6;
  const int m0 = blockIdx.x * 128;

  const int q = tid & 3, rr = tid >> 2;        // rr 0..63
  const unsigned short* gA0 = A + (size_t)(m0 + rr) * H1_DIM + q * 8;
  const unsigned short* gA1 = gA0 + (size_t)64 * H1_DIM;
  const unsigned short* gB0 = B + (size_t)rr * H1_DIM + q * 8;
  const unsigned short* gB1 = gB0 + (size_t)64 * H1_DIM;
  const int lo = wave * 512;

  const int wr = wave >> 1, wc = wave & 1;
  const int fr = lane & 15, fk = lane >> 4;
  const int oA = (wr * 64 + fr) * 32 + fk * 8;
  const int oB = (wc * 64 + fr) * 32 + fk * 8;

  f32x4 acc[4][4] = {};
  {
    gload16(gA0, &sA[0][lo]);
    gload16(gA1, &sA[0][2048 + lo]);
    gload16(gB0, &sB[0][lo]);
    gload16(gB1, &sB[0][2048 + lo]);
  }
  for (int ks = 0; ks < 8; ++ks) {
    const int cur = ks & 1;
    if (ks + 1 < 8) {
      const int ko = (ks + 1) * 32;
      gload16(gA0 + ko, &sA[cur ^ 1][lo]);
      gload16(gA1 + ko, &sA[cur ^ 1][2048 + lo]);
      gload16(gB0 + ko, &sB[cur ^ 1][lo]);
      gload16(gB1 + ko, &sB[cur ^ 1][2048 + lo]);
      asm volatile("s_waitcnt vmcnt(4)" ::: "memory");
    } else {
      asm volatile("s_waitcnt vmcnt(0)" ::: "memory");
    }
    __builtin_amdgcn_sched_barrier(0);
    __builtin_amdgcn_s_barrier();
    bf16x8 av[4], bv[4];
#pragma unroll
    for (int mi = 0; mi < 4; ++mi) av[mi] = *(const bf16x8*)&sA[cur][oA + mi * 512];
#pragma unroll
    for (int ni = 0; ni < 4; ++ni) bv[ni] = *(const bf16x8*)&sB[cur][oB + ni * 512];
    asm volatile("s_waitcnt lgkmcnt(0)" ::: "memory");
    __builtin_amdgcn_sched_barrier(0);
    __builtin_amdgcn_s_barrier();
#pragma unroll
    for (int mi = 0; mi < 4; ++mi)
#pragma unroll
      for (int ni = 0; ni < 4; ++ni)
        acc[mi][ni] = __builtin_amdgcn_mfma_f32_16x16x32_bf16(
            av[mi], bv[ni], acc[mi][ni], 0, 0, 0);
  }
  // epilogue: bias, store Y2 (NT), per-column partial stats
  float sc[4] = {0.f, 0.f, 0.f, 0.f}, sq[4] = {0.f, 0.f, 0.f, 0.f};
#pragma unroll
  for (int ni = 0; ni < 4; ++ni) {
    int col = wc * 64 + ni * 16 + fr;
    float bcol = b2[col];
#pragma unroll
    for (int mi = 0; mi < 4; ++mi)
#pragma unroll
      for (int r = 0; r < 4; ++r) {
        int row = m0 + wr * 64 + mi * 16 + fk * 4 + r;
        float y = acc[mi][ni][r] + bcol;
        __builtin_nontemporal_store(y, &Y2[(size_t)row * H2_DIM + col]);
        sc[ni] += y; sq[ni] += y * y;
      }
  }
  const int slot = wr * 4 + fk;
#pragma unroll
  for (int ni = 0; ni < 4; ++ni) {
    int col = wc * 64 + ni * 16 + fr;
    redS[slot][col] = sc[ni];
    redQ[slot][col] = sq[ni];
  }
  __syncthreads();
  if (tid < H2_DIM) {
    float s = 0.f, s2 = 0.f;
#pragma unroll
    for (int sl = 0; sl < 8; ++sl) { s += redS[sl][tid]; s2 += redQ[sl][tid]; }
    ps[blockIdx.x * H2_DIM + tid] = s;
    pq[blockIdx.x * H2_DIM + tid] = s2;
  }
}

// -- final: deterministic stats reduce + BN2 + relu + Wout dot + sigmoid -----
__global__ __launch_bounds__(256) void k_final(
    const float* __restrict__ Y2, const float* __restrict__ ps,
    const float* __restrict__ pq, const float* __restrict__ g2,
    const float* __restrict__ be2, const float* __restrict__ Wout,
    const float* __restrict__ bout, const float* __restrict__ fm12,
    float* __restrict__ out) {
  const int tid = threadIdx.x, wave = tid >> 6, lane = tid & 63;
  __shared__ float sm[H2_DIM], sr[H2_DIM], sg[H2_DIM], sbe[H2_DIM], sw[H2_DIM];
  if (tid < H2_DIM) {
    float s = 0.f, s2 = 0.f;
    for (int g = 0; g < 32; ++g) {             // fixed order -> deterministic
      s += ps[g * H2_DIM + tid];
      s2 += pq[g * H2_DIM + tid];
    }
    float m = s * (1.f / BS);
    float v = s2 * (1.f / BS) - m * m;
    sm[tid] = m; sr[tid] = rsqrtf(v + 1e-5f);
    sg[tid] = g2[tid]; sbe[tid] = be2[tid]; sw[tid] = Wout[tid];
  }
  __syncthreads();
  const float bo = bout[0];
  for (int ii = 0; ii < 16; ++ii) {
    int s = blockIdx.x * 64 + wave * 16 + ii;
    float acc = 0.f;
#pragma unroll
    for (int nn = 0; nn < 2; ++nn) {
      int n = lane + nn * 64;
      float y = __builtin_nontemporal_load(&Y2[(size_t)s * H2_DIM + n]);
      float h = (y - sm[n]) * sr[n] * sg[n] + sbe[n];
      acc += fmaxf(h, 0.f) * sw[n];
    }
#pragma unroll
    for (int off = 32; off; off >>= 1) acc += __shfl_down(acc, off);
    if (lane == 0) {
      float logit = fm12[s] + acc + bo;
      out[s] = 1.f / (1.f + expf(-logit));
    }
  }
}

extern "C" void kernel_launch(void* const* d_in, const int* in_sizes, int n_in,
                              void* d_out, int out_size, void* d_ws, size_t ws_size,
                              hipStream_t stream) {
  const int*   Xs     = (const int*)d_in[0];
  const float* Xd     = (const float*)d_in[1];
  const float* fm1e   = (const float*)d_in[2];
  const float* bias   = (const float*)d_in[3];
  const float* fm1dW  = (const float*)d_in[4];
  const float* fm1db  = (const float*)d_in[5];
  const float* emb    = (const float*)d_in[6];
  const float* dW     = (const float*)d_in[7];
  const float* db_    = (const float*)d_in[8];
  const float* W1     = (const float*)d_in[9];
  const float* b1     = (const float*)d_in[10];
  const float* g1     = (const float*)d_in[11];
  const float* be1    = (const float*)d_in[12];
  const float* W2     = (const float*)d_in[13];
  const float* b2     = (const float*)d_in[14];
  const float* g2     = (const float*)d_in[15];
  const float* be2    = (const float*)d_in[16];
  const float* Wout   = (const float*)d_in[17];
  const float* bout   = (const float*)d_in[18];
  float* out = (float*)d_out;

  char* w = (char*)d_ws;
  unsigned short* Dnn = (unsigned short*)w; w += (size_t)BS * DNN_IN * 2;      // 88.6 MB
  unsigned short* W1b = (unsigned short*)w; w += (size_t)H1_DIM * DNN_IN * 2;  // 5.5 MB
  unsigned short* W2b = (unsigned short*)w; w += (size_t)H2_DIM * H1_DIM * 2;
  unsigned short* dWb = (unsigned short*)w; w += (size_t)DNN_IN * 32 * 2;      // 692 KB
  float* fm12 = (float*)w;  w += (size_t)BS * 4;
  unsigned short* Ypart = (unsigned short*)w; w += (size_t)NP1 * BS * H1_DIM * 2; // 16.8 MB
  float* Y1 = (float*)w;    w += (size_t)BS * H1_DIM * 4;
  unsigned short* H1b = (unsigned short*)w; w += (size_t)BS * H1_DIM * 2;
  float* Y2 = (float*)w;    w += (size_t)BS * H2_DIM * 4;
  float* ps1 = (float*)w;   w += 256 * H1_DIM * 4;
  float* pq1 = (float*)w;   w += 256 * H1_DIM * 4;
  float* ps2 = (float*)w;   w += 32 * H2_DIM * 4;
  float* pq2 = (float*)w;   w += 32 * H2_DIM * 4;

  k_gather<<<BS, 256, 0, stream>>>(Xs, emb, fm1e, bias, fm1dW, fm1db, Xd,
                                   W1, W2, dW, db_, W1b, W2b, dWb, Dnn, fm12);
  k_gemm1<<<64 * NP1, 256, 0, stream>>>(Dnn, W1b, dWb, Xd, Ypart);
  k_stat1<<<256, 256, 0, stream>>>(Ypart, b1, Y1, ps1, pq1);
  k_apply1<<<256, 256, 0, stream>>>(Y1, ps1, pq1, g1, be1, H1b);
  k_gemm2<<<32, 256, 0, stream>>>(H1b, W2b, b2, Y2, ps2, pq2);
  k_final<<<BS / 64, 256, 0, stream>>>(Y2, ps2, pq2, g2, be2, Wout, bout, fm12, out);
}

// Round 9
// 180.136 us; speedup vs baseline: 1.1088x; 1.1088x over previous
//
#include <hip/hip_runtime.h>

typedef __bf16 bf16x8 __attribute__((ext_vector_type(8)));
typedef float f32x4 __attribute__((ext_vector_type(4)));

#define F_FIELDS 26
#define V_FIELD  8000
#define V_TOT    208000
#define D_EMBD   16
#define DNN_IN   10816   // 26*26*16
#define BS       4096
#define ND       13
#define H1_DIM   256
#define H2_DIM   128
#define NP1      8       // gemm1 split-K planes

__device__ __forceinline__ unsigned short f2bf(float f) {
  unsigned u = __float_as_uint(f);
  u += 0x7fffu + ((u >> 16) & 1u);      // round-to-nearest-even
  return (unsigned short)(u >> 16);
}
__device__ __forceinline__ float bf2f(unsigned short h) {
  return __uint_as_float(((unsigned)h) << 16);
}
__device__ __forceinline__ float bflo(unsigned u) { return __uint_as_float(u << 16); }
__device__ __forceinline__ float bfhi(unsigned u) { return __uint_as_float(u & 0xffff0000u); }
__device__ __forceinline__ unsigned packbf(float a, float b) {
  return (unsigned)f2bf(a) | ((unsigned)f2bf(b) << 16);
}

__device__ __forceinline__ void gload16(const void* g, void* l) {
  __builtin_amdgcn_global_load_lds(
      (const __attribute__((address_space(1))) unsigned int*)g,
      (__attribute__((address_space(3))) unsigned int*)l, 16, 0, 0);
}

__device__ __forceinline__ float dot8bf(uint4 a, uint4 b) {
  const unsigned* pa = (const unsigned*)&a;
  const unsigned* pb = (const unsigned*)&b;
  float s = 0.f;
#pragma unroll
  for (int k = 0; k < 4; ++k)
    s += bflo(pa[k]) * bflo(pb[k]) + bfhi(pa[k]) * bfhi(pb[k]);
  return s;
}

// ------- gather: A tensor + fm1 + fm2 + W1/W2/dense-W bf16 conversion -------
// block = one sample. A[b,i,j,:] = emb[i, X[b,j], :]; 676 rows of 16 floats.
__global__ __launch_bounds__(256) void k_gather(
    const int* __restrict__ Xs, const float* __restrict__ emb,
    const float* __restrict__ fm1_emb, const float* __restrict__ bias,
    const float* __restrict__ fm1dW, const float* __restrict__ fm1db,
    const float* __restrict__ Xd,
    const float* __restrict__ W1, const float* __restrict__ W2,
    const float* __restrict__ dW, const float* __restrict__ db_,
    unsigned short* __restrict__ W1b, unsigned short* __restrict__ W2b,
    unsigned short* __restrict__ dWb,
    unsigned short* __restrict__ Abf, float* __restrict__ fm12) {
  const int b = blockIdx.x;
  const int tid = threadIdx.x;
  const int lane = tid & 63, wave = tid >> 6;
  __shared__ int   sidx[F_FIELDS];
  __shared__ float sc1[F_FIELDS];
  __shared__ __align__(16) unsigned short As[676 * 16];  // bf16, 21.6 KB
  __shared__ float wred[4];

  if (tid < F_FIELDS) {
    int v = Xs[b * F_FIELDS + tid] + tid * V_FIELD;
    sidx[tid] = v;
    sc1[tid] = fm1_emb[v];
  }
  __syncthreads();

  const int q = tid & 3, rbase = tid >> 2;   // 4 lanes per row (float4 each)
  float4 vv[11];
#pragma unroll
  for (int it = 0; it < 11; ++it) {          // issue all gathers first (MLP)
    int r = rbase + it * 64;
    if (r < 676) {
      int i = r / 26, j = r - i * 26;
      const float* src = emb + ((size_t)i * V_TOT + sidx[j]) * D_EMBD + q * 4;
      vv[it] = *(const float4*)src;
    }
  }
  // W1/W2 -> bf16 conversion: independent work overlapping gather latency
  const int n1 = H1_DIM * DNN_IN, n2 = H2_DIM * H1_DIM;
  for (int t = b * 256 + tid; t < n1 + n2; t += BS * 256) {
    if (t < n1) W1b[t] = f2bf(W1[t]);
    else        W2b[t - n1] = f2bf(W2[t - n1]);
  }
  // dense-W augmented bf16 table (K=32): [0..12]=w, [13]=db, [14..31]=0
  for (int e = b * 256 + tid; e < DNN_IN; e += BS * 256) {
    unsigned short row[32];
#pragma unroll
    for (int k = 0; k < 13; ++k) row[k] = f2bf(dW[e * 13 + k]);
    row[13] = f2bf(db_[e]);
#pragma unroll
    for (int k = 14; k < 32; ++k) row[k] = 0;
#pragma unroll
    for (int k = 0; k < 32; ++k) dWb[e * 32 + k] = row[k];
  }
#pragma unroll
  for (int it = 0; it < 11; ++it) {
    int r = rbase + it * 64;
    if (r < 676) {
      unsigned lo = packbf(vv[it].x, vv[it].y);
      unsigned hi = packbf(vv[it].z, vv[it].w);
      unsigned long long pk = (unsigned long long)lo |
                              ((unsigned long long)hi << 32);
      *(unsigned long long*)&As[r * 16 + q * 4] = pk;
      *(unsigned long long*)&Abf[(size_t)b * DNN_IN + r * 16 + q * 4] = pk;
    }
  }
  __syncthreads();

  // fm2 = sum_{i<j} dot(A[b,i,j,:], A[b,j,i,:]) ; 325 pairs (bf16 products)
  float acc2 = 0.f;
  for (int p = tid; p < 325; p += 256) {
    float disc = sqrtf((float)(2601 - 8 * p));   // exact for perfect squares
    int i = (int)((51.f - disc) * 0.5f);
    int cum = 25 * i - ((i * (i - 1)) >> 1);
    int j = i + 1 + (p - cum);
    const unsigned short* r1 = &As[(i * 26 + j) * 16];
    const unsigned short* r2 = &As[(j * 26 + i) * 16];
    acc2 += dot8bf(*(const uint4*)r1, *(const uint4*)r2);
    acc2 += dot8bf(*(const uint4*)(r1 + 8), *(const uint4*)(r2 + 8));
  }
#pragma unroll
  for (int off = 32; off; off >>= 1) acc2 += __shfl_down(acc2, off);
  if (lane == 0) wred[wave] = acc2;
  __syncthreads();
  if (tid == 0) {
    float fm2 = wred[0] + wred[1] + wred[2] + wred[3];
    float f1 = bias[0] + fm1db[0];
#pragma unroll
    for (int j = 0; j < F_FIELDS; ++j) f1 += sc1[j];
    for (int k = 0; k < ND; ++k) f1 += Xd[b * ND + k] * fm1dW[k];
    fm12[b] = f1 + fm2;
  }
}

// ---- GEMM1 fused-dense: Y1part = (A + relu(Xd@dW^T+db)) @ W1^T -------------
// 64x256 tile, depth-2 3-buffer pipeline, split-K 8 (plane = id&7 per XCD).
__global__ __launch_bounds__(256) void k_gemm1(
    const unsigned short* __restrict__ A, const unsigned short* __restrict__ B,
    const unsigned short* __restrict__ dWb, const float* __restrict__ Xd,
    unsigned short* __restrict__ C) {
  __shared__ __align__(16) unsigned short sA[3][64 * 32];    // 12 KB
  __shared__ __align__(16) unsigned short sB[3][256 * 32];   // 48 KB
  __shared__ __align__(16) unsigned short sWd[3][1024];      // 6 KB (32e x 32k)
  __shared__ __align__(16) unsigned short sD[64 * 32];       // 4 KB (E-tile)
  __shared__ __align__(16) unsigned short sXd[64 * 32];      // 4 KB (augmented)
  const int tid = threadIdx.x;
  const int lane = tid & 63, w = tid >> 6;
  const int id = blockIdx.x;
  const int p = id & 7, mt = id >> 3;
  const int m0 = mt * 64;
  const int s0 = (338 * p) >> 3, s1 = (338 * (p + 1)) >> 3;
  C += (size_t)p * ((size_t)BS * H1_DIM);

  // stage augmented Xd rows (once): [s][0..12]=xd, [13]=1.0, [14..31]=0
  if (tid < 64) {
    const float* xr = Xd + (size_t)(m0 + tid) * ND;
    unsigned short row[32];
#pragma unroll
    for (int k = 0; k < 13; ++k) row[k] = f2bf(xr[k]);
    row[13] = 0x3F80;                          // bf16(1.0)
#pragma unroll
    for (int k = 14; k < 32; ++k) row[k] = 0;
#pragma unroll
    for (int k = 0; k < 32; ++k) sXd[tid * 32 + k] = row[k];
  }
  __syncthreads();

  const int q = tid & 3, rr = tid >> 2;       // rr 0..63
  const unsigned short* gA  = A + (size_t)(m0 + rr) * DNN_IN + q * 8;
  const unsigned short* gB0 = B + (size_t)rr * DNN_IN + q * 8;
  const int fr = lane & 15, fk = lane >> 4;
  const int oA = fr * 32 + fk * 8;             // frag base (rows=samples)
  const int oB = (w * 64 + fr) * 32 + fk * 8;

  // D-gen (swapped operands): A-op = dW_aug rows, B-op = Xd_aug samples.
  const bf16x8 bvd = *(const bf16x8*)&sXd[(w * 16 + fr) * 32 + fk * 8];
  const int erow = (w * 16 + fr) * 32;         // sD row base for this lane
  const int ecol = fk * 4;                     // 4 consecutive e per mfma reg

  f32x4 acc[4][4] = {};
  const f32x4 zf = {0.f, 0.f, 0.f, 0.f};

#define STAGE1(ks, bi) do { const int ko_ = (ks) * 32;                      \
    gload16(gA + ko_, &sA[bi][tid * 8]);                                    \
    gload16(gB0 + ko_, &sB[bi][tid * 8]);                                   \
    gload16(gB0 + (size_t)64 * DNN_IN + ko_, &sB[bi][2048 + tid * 8]);      \
    gload16(gB0 + (size_t)128 * DNN_IN + ko_, &sB[bi][4096 + tid * 8]);     \
    gload16(gB0 + (size_t)192 * DNN_IN + ko_, &sB[bi][6144 + tid * 8]);     \
    gload16(dWb + (size_t)ko_ * 32 + (size_t)lane * 8, &sWd[bi][lane * 8]); \
    gload16(dWb + (size_t)ko_ * 32 + 512 + (size_t)lane * 8,                \
            &sWd[bi][512 + lane * 8]); } while (0)

  STAGE1(s0, 0);
  if (s0 + 1 < s1) STAGE1(s0 + 1, 1);
  if (s0 + 2 < s1) STAGE1(s0 + 2, 2);

  int bi = 0;
  for (int ks = s0; ks < s1; ++ks) {
    if (ks + 2 < s1)      asm volatile("s_waitcnt vmcnt(14)" ::: "memory");
    else if (ks + 1 < s1) asm volatile("s_waitcnt vmcnt(7)" ::: "memory");
    else                  asm volatile("s_waitcnt vmcnt(0)" ::: "memory");
    __builtin_amdgcn_sched_barrier(0);
    __builtin_amdgcn_s_barrier();             // bar1: buf bi staged
    bf16x8 aw0 = *(const bf16x8*)&sWd[bi][fr * 32 + fk * 8];
    bf16x8 aw1 = *(const bf16x8*)&sWd[bi][(16 + fr) * 32 + fk * 8];
    bf16x8 bv[4];
#pragma unroll
    for (int ni = 0; ni < 4; ++ni) bv[ni] = *(const bf16x8*)&sB[bi][oB + ni * 512];
    uint2 a0 = *(const uint2*)&sA[bi][erow + ecol];
    uint2 a1 = *(const uint2*)&sA[bi][erow + 16 + ecol];
    asm volatile("s_waitcnt lgkmcnt(0)" ::: "memory");
    __builtin_amdgcn_sched_barrier(0);
    f32x4 d0 = __builtin_amdgcn_mfma_f32_16x16x32_bf16(aw0, bvd, zf, 0, 0, 0);
    f32x4 d1 = __builtin_amdgcn_mfma_f32_16x16x32_bf16(aw1, bvd, zf, 0, 0, 0);
    uint2 e0, e1;
    e0.x = packbf(bflo(a0.x) + fmaxf(d0[0], 0.f), bfhi(a0.x) + fmaxf(d0[1], 0.f));
    e0.y = packbf(bflo(a0.y) + fmaxf(d0[2], 0.f), bfhi(a0.y) + fmaxf(d0[3], 0.f));
    e1.x = packbf(bflo(a1.x) + fmaxf(d1[0], 0.f), bfhi(a1.x) + fmaxf(d1[1], 0.f));
    e1.y = packbf(bflo(a1.y) + fmaxf(d1[2], 0.f), bfhi(a1.y) + fmaxf(d1[3], 0.f));
    *(uint2*)&sD[erow + ecol] = e0;
    *(uint2*)&sD[erow + 16 + ecol] = e1;
    asm volatile("s_waitcnt lgkmcnt(0)" ::: "memory");
    __builtin_amdgcn_sched_barrier(0);
    __builtin_amdgcn_s_barrier();             // bar2: sD(E) complete
    if (ks + 3 < s1) STAGE1(ks + 3, bi);
    bf16x8 ev[4];
#pragma unroll
    for (int mi = 0; mi < 4; ++mi) ev[mi] = *(const bf16x8*)&sD[oA + mi * 512];
    asm volatile("s_waitcnt lgkmcnt(0)" ::: "memory");
    __builtin_amdgcn_sched_barrier(0);
#pragma unroll
    for (int mi = 0; mi < 4; ++mi)
#pragma unroll
      for (int ni = 0; ni < 4; ++ni)
        acc[mi][ni] = __builtin_amdgcn_mfma_f32_16x16x32_bf16(
            ev[mi], bv[ni], acc[mi][ni], 0, 0, 0);
    bi = bi + 1; if (bi == 3) bi = 0;
  }
#pragma unroll
  for (int mi = 0; mi < 4; ++mi)
#pragma unroll
    for (int ni = 0; ni < 4; ++ni)
#pragma unroll
      for (int r = 0; r < 4; ++r) {
        int row = m0 + mi * 16 + fk * 4 + r;
        int col = w * 64 + ni * 16 + fr;
        C[(size_t)row * H1_DIM + col] = f2bf(acc[mi][ni][r]);
      }
#undef STAGE1
}

// -------- stat1: per-group partial column stats from 8 bf16 planes ----------
__global__ __launch_bounds__(256) void k_stat1(
    const unsigned short* __restrict__ Yp, const float* __restrict__ b1,
    float* __restrict__ ps, float* __restrict__ pq) {
  const int g = blockIdx.x, n = threadIdx.x;   // 256 groups x 16 rows
  const size_t plane = (size_t)BS * H1_DIM;
  float s = 0.f, s2 = 0.f;
  float bn = b1[n];
  for (int bb = 0; bb < 16; ++bb) {
    size_t o = (size_t)(g * 16 + bb) * H1_DIM + n;
    float y = bn;
#pragma unroll
    for (int pp = 0; pp < NP1; ++pp) y += bf2f(Yp[o + pp * plane]);
    s += y; s2 += y * y;
  }
  ps[g * H1_DIM + n] = s;
  pq[g * H1_DIM + n] = s2;
}

// ---- apply1: stats reduce + recompute y from planes + BN1 + relu -> H1b ----
// y recomputed with IDENTICAL summation order as stat1 -> bit-consistent.
__global__ __launch_bounds__(256) void k_apply1(
    const unsigned short* __restrict__ Yp, const float* __restrict__ b1,
    const float* __restrict__ ps, const float* __restrict__ pq,
    const float* __restrict__ g1, const float* __restrict__ be1,
    unsigned short* __restrict__ H1b) {
  const int g = blockIdx.x, n = threadIdx.x;
  const size_t plane = (size_t)BS * H1_DIM;
  float s = 0.f, s2 = 0.f;
  for (int gg = 0; gg < 256; ++gg) {           // fixed order -> deterministic
    s += ps[gg * H1_DIM + n];
    s2 += pq[gg * H1_DIM + n];
  }
  float m = s * (1.f / BS);
  float v = s2 * (1.f / BS) - m * m;
  float r = rsqrtf(v + 1e-5f);
  float ga = g1[n], bb_ = be1[n];
  float bn = b1[n];
  for (int bb = 0; bb < 16; ++bb) {
    size_t o = (size_t)(g * 16 + bb) * H1_DIM + n;
    float y = bn;
#pragma unroll
    for (int pp = 0; pp < NP1; ++pp) y += bf2f(Yp[o + pp * plane]);
    float h = (y - m) * r * ga + bb_;
    H1b[o] = f2bf(fmaxf(h, 0.f));
  }
}

// -------- GEMM2 (32 blocks) + bias + per-block partial column stats ---------
__global__ __launch_bounds__(256) void k_gemm2(
    const unsigned short* __restrict__ A, const unsigned short* __restrict__ B,
    const float* __restrict__ b2, float* __restrict__ Y2,
    float* __restrict__ ps, float* __restrict__ pq) {
  __shared__ __align__(16) unsigned short sA[2][128 * 32];
  __shared__ __align__(16) unsigned short sB[2][128 * 32];
  __shared__ float redS[8][H2_DIM];
  __shared__ float redQ[8][H2_DIM];
  const int tid = threadIdx.x;
  const int lane = tid & 63, wave = tid >> 6;
  const int m0 = blockIdx.x * 128;

  const int q = tid & 3, rr = tid >> 2;        // rr 0..63
  const unsigned short* gA0 = A + (size_t)(m0 + rr) * H1_DIM + q * 8;
  const unsigned short* gA1 = gA0 + (size_t)64 * H1_DIM;
  const unsigned short* gB0 = B + (size_t)rr * H1_DIM + q * 8;
  const unsigned short* gB1 = gB0 + (size_t)64 * H1_DIM;
  const int lo = wave * 512;

  const int wr = wave >> 1, wc = wave & 1;
  const int fr = lane & 15, fk = lane >> 4;
  const int oA = (wr * 64 + fr) * 32 + fk * 8;
  const int oB = (wc * 64 + fr) * 32 + fk * 8;

  f32x4 acc[4][4] = {};
  {
    gload16(gA0, &sA[0][lo]);
    gload16(gA1, &sA[0][2048 + lo]);
    gload16(gB0, &sB[0][lo]);
    gload16(gB1, &sB[0][2048 + lo]);
  }
  for (int ks = 0; ks < 8; ++ks) {
    const int cur = ks & 1;
    if (ks + 1 < 8) {
      const int ko = (ks + 1) * 32;
      gload16(gA0 + ko, &sA[cur ^ 1][lo]);
      gload16(gA1 + ko, &sA[cur ^ 1][2048 + lo]);
      gload16(gB0 + ko, &sB[cur ^ 1][lo]);
      gload16(gB1 + ko, &sB[cur ^ 1][2048 + lo]);
      asm volatile("s_waitcnt vmcnt(4)" ::: "memory");
    } else {
      asm volatile("s_waitcnt vmcnt(0)" ::: "memory");
    }
    __builtin_amdgcn_sched_barrier(0);
    __builtin_amdgcn_s_barrier();
    bf16x8 av[4], bv[4];
#pragma unroll
    for (int mi = 0; mi < 4; ++mi) av[mi] = *(const bf16x8*)&sA[cur][oA + mi * 512];
#pragma unroll
    for (int ni = 0; ni < 4; ++ni) bv[ni] = *(const bf16x8*)&sB[cur][oB + ni * 512];
    asm volatile("s_waitcnt lgkmcnt(0)" ::: "memory");
    __builtin_amdgcn_sched_barrier(0);
    __builtin_amdgcn_s_barrier();
#pragma unroll
    for (int mi = 0; mi < 4; ++mi)
#pragma unroll
      for (int ni = 0; ni < 4; ++ni)
        acc[mi][ni] = __builtin_amdgcn_mfma_f32_16x16x32_bf16(
            av[mi], bv[ni], acc[mi][ni], 0, 0, 0);
  }
  // epilogue: bias, store Y2, per-column partial stats over this block's rows
  float sc[4] = {0.f, 0.f, 0.f, 0.f}, sq[4] = {0.f, 0.f, 0.f, 0.f};
#pragma unroll
  for (int ni = 0; ni < 4; ++ni) {
    int col = wc * 64 + ni * 16 + fr;
    float bcol = b2[col];
#pragma unroll
    for (int mi = 0; mi < 4; ++mi)
#pragma unroll
      for (int r = 0; r < 4; ++r) {
        int row = m0 + wr * 64 + mi * 16 + fk * 4 + r;
        float y = acc[mi][ni][r] + bcol;
        Y2[(size_t)row * H2_DIM + col] = y;
        sc[ni] += y; sq[ni] += y * y;
      }
  }
  const int slot = wr * 4 + fk;
#pragma unroll
  for (int ni = 0; ni < 4; ++ni) {
    int col = wc * 64 + ni * 16 + fr;
    redS[slot][col] = sc[ni];
    redQ[slot][col] = sq[ni];
  }
  __syncthreads();
  if (tid < H2_DIM) {
    float s = 0.f, s2 = 0.f;
#pragma unroll
    for (int sl = 0; sl < 8; ++sl) { s += redS[sl][tid]; s2 += redQ[sl][tid]; }
    ps[blockIdx.x * H2_DIM + tid] = s;
    pq[blockIdx.x * H2_DIM + tid] = s2;
  }
}

// -- final: deterministic stats reduce + BN2 + relu + Wout dot + sigmoid -----
__global__ __launch_bounds__(256) void k_final(
    const float* __restrict__ Y2, const float* __restrict__ ps,
    const float* __restrict__ pq, const float* __restrict__ g2,
    const float* __restrict__ be2, const float* __restrict__ Wout,
    const float* __restrict__ bout, const float* __restrict__ fm12,
    float* __restrict__ out) {
  const int tid = threadIdx.x, wave = tid >> 6, lane = tid & 63;
  __shared__ float sm[H2_DIM], sr[H2_DIM], sg[H2_DIM], sbe[H2_DIM], sw[H2_DIM];
  if (tid < H2_DIM) {
    float s = 0.f, s2 = 0.f;
    for (int g = 0; g < 32; ++g) {             // fixed order -> deterministic
      s += ps[g * H2_DIM + tid];
      s2 += pq[g * H2_DIM + tid];
    }
    float m = s * (1.f / BS);
    float v = s2 * (1.f / BS) - m * m;
    sm[tid] = m; sr[tid] = rsqrtf(v + 1e-5f);
    sg[tid] = g2[tid]; sbe[tid] = be2[tid]; sw[tid] = Wout[tid];
  }
  __syncthreads();
  const float bo = bout[0];
  for (int ii = 0; ii < 16; ++ii) {
    int s = blockIdx.x * 64 + wave * 16 + ii;
    float acc = 0.f;
#pragma unroll
    for (int nn = 0; nn < 2; ++nn) {
      int n = lane + nn * 64;
      float y = Y2[(size_t)s * H2_DIM + n];
      float h = (y - sm[n]) * sr[n] * sg[n] + sbe[n];
      acc += fmaxf(h, 0.f) * sw[n];
    }
#pragma unroll
    for (int off = 32; off; off >>= 1) acc += __shfl_down(acc, off);
    if (lane == 0) {
      float logit = fm12[s] + acc + bo;
      out[s] = 1.f / (1.f + expf(-logit));
    }
  }
}

extern "C" void kernel_launch(void* const* d_in, const int* in_sizes, int n_in,
                              void* d_out, int out_size, void* d_ws, size_t ws_size,
                              hipStream_t stream) {
  const int*   Xs     = (const int*)d_in[0];
  const float* Xd     = (const float*)d_in[1];
  const float* fm1e   = (const float*)d_in[2];
  const float* bias   = (const float*)d_in[3];
  const float* fm1dW  = (const float*)d_in[4];
  const float* fm1db  = (const float*)d_in[5];
  const float* emb    = (const float*)d_in[6];
  const float* dW     = (const float*)d_in[7];
  const float* db_    = (const float*)d_in[8];
  const float* W1     = (const float*)d_in[9];
  const float* b1     = (const float*)d_in[10];
  const float* g1     = (const float*)d_in[11];
  const float* be1    = (const float*)d_in[12];
  const float* W2     = (const float*)d_in[13];
  const float* b2     = (const float*)d_in[14];
  const float* g2     = (const float*)d_in[15];
  const float* be2    = (const float*)d_in[16];
  const float* Wout   = (const float*)d_in[17];
  const float* bout   = (const float*)d_in[18];
  float* out = (float*)d_out;

  char* w = (char*)d_ws;
  unsigned short* Dnn = (unsigned short*)w; w += (size_t)BS * DNN_IN * 2;      // 88.6 MB
  unsigned short* W1b = (unsigned short*)w; w += (size_t)H1_DIM * DNN_IN * 2;  // 5.5 MB
  unsigned short* W2b = (unsigned short*)w; w += (size_t)H2_DIM * H1_DIM * 2;
  unsigned short* dWb = (unsigned short*)w; w += (size_t)DNN_IN * 32 * 2;      // 692 KB
  float* fm12 = (float*)w;  w += (size_t)BS * 4;
  unsigned short* Ypart = (unsigned short*)w; w += (size_t)NP1 * BS * H1_DIM * 2; // 16.8 MB
  unsigned short* H1b = (unsigned short*)w; w += (size_t)BS * H1_DIM * 2;
  float* Y2 = (float*)w;    w += (size_t)BS * H2_DIM * 4;
  float* ps1 = (float*)w;   w += 256 * H1_DIM * 4;
  float* pq1 = (float*)w;   w += 256 * H1_DIM * 4;
  float* ps2 = (float*)w;   w += 32 * H2_DIM * 4;
  float* pq2 = (float*)w;   w += 32 * H2_DIM * 4;

  k_gather<<<BS, 256, 0, stream>>>(Xs, emb, fm1e, bias, fm1dW, fm1db, Xd,
                                   W1, W2, dW, db_, W1b, W2b, dWb, Dnn, fm12);
  k_gemm1<<<64 * NP1, 256, 0, stream>>>(Dnn, W1b, dWb, Xd, Ypart);
  k_stat1<<<256, 256, 0, stream>>>(Ypart, b1, ps1, pq1);
  k_apply1<<<256, 256, 0, stream>>>(Ypart, b1, ps1, pq1, g1, be1, H1b);
  k_gemm2<<<32, 256, 0, stream>>>(H1b, W2b, b2, Y2, ps2, pq2);
  k_final<<<BS / 64, 256, 0, stream>>>(Y2, ps2, pq2, g2, be2, Wout, bout, fm12, out);
}